// Round 1
// baseline (89.772 us; speedup 1.0000x reference)
//
#include <hip/hip_runtime.h>

#define BD 128   // D
#define SL 512   // L
#define NB 4     // B

__device__ __forceinline__ float rcp_fast(float x) { return __builtin_amdgcn_rcpf(x); }

// K0: transpose Wu, Ww (row-major (out,in)) -> WT[k][o]. 64 blocks, trivial.
__global__ __launch_bounds__(256) void k_tr(const float* __restrict__ Wu,
                                            const float* __restrict__ Ww,
                                            float* __restrict__ WuT,
                                            float* __restrict__ WwT) {
    int idx = blockIdx.x * 256 + threadIdx.x;   // 0..16383
    int k = idx >> 7, o = idx & 127;
    WuT[idx] = Wu[o * BD + k];
    WwT[idx] = Ww[o * BD + k];
}

// K1: qu = inp@Wu.T, kw = inp@Ww.T. 2 rows/block, 1024 blocks.
// XCD-aware swizzle: batch b pinned to XCD pair {2b, 2b+1} (blk%8 = XCD heuristic)
// so Equ/Ekw writes land in the L2 that k_attn will read them from.
// Equ layout: [b][c=d>>2][j][d&3] -> k_attn reads a lane-consecutive float4 per (c,j).
__global__ __launch_bounds__(256) void k_qk(const float* __restrict__ inp,
                                            const float* __restrict__ WuT,
                                            const float* __restrict__ WwT,
                                            float* __restrict__ Equ,
                                            float* __restrict__ Ekw) {
    __shared__ float sx[2][BD];
    const int t = threadIdx.x, m = t >> 7, o = t & 127;
    const int blk = blockIdx.x;
    const int x   = blk & 7;                // XCD (round-robin heuristic)
    const int b   = x >> 1;                 // batch pinned to XCD pair
    const int rp  = (blk >> 3) * 2 + (x & 1);   // row-pair 0..255
    const int r0  = b * SL + rp * 2;        // global row (even)
    const int l0  = rp * 2;

    sx[t >> 7][t & 127] = inp[(size_t)r0 * BD + t];   // coalesced 512 floats
    __syncthreads();

    const float* WT = m ? WwT : WuT;        // WT[k][o], coalesced + L2-hot
    float acc0 = 0.f, acc1 = 0.f;
    #pragma unroll 4
    for (int k = 0; k < BD; k += 4) {       // 16 loads in flight
        float w0 = WT[(k + 0) * BD + o];
        float w1 = WT[(k + 1) * BD + o];
        float w2 = WT[(k + 2) * BD + o];
        float w3 = WT[(k + 3) * BD + o];
        float4 x0 = *(const float4*)&sx[0][k];
        float4 x1 = *(const float4*)&sx[1][k];
        acc0 = fmaf(x0.x, w0, acc0); acc0 = fmaf(x0.y, w1, acc0);
        acc0 = fmaf(x0.z, w2, acc0); acc0 = fmaf(x0.w, w3, acc0);
        acc1 = fmaf(x1.x, w0, acc1); acc1 = fmaf(x1.y, w1, acc1);
        acc1 = fmaf(x1.z, w2, acc1); acc1 = fmaf(x1.w, w3, acc1);
    }

    if (m == 0) {
        // Equ[b][c][j][comp], c = o>>2, comp = o&3
        size_t base = ((size_t)b * 32 + (o >> 2)) * (SL * 4) + (size_t)l0 * 4 + (o & 3);
        Equ[base]     = __expf(2.f * acc0);   // j = l0
        Equ[base + 4] = __expf(2.f * acc1);   // j = l0+1
    } else {
        Ekw[(size_t)(r0 + 0) * BD + o] = __expf(2.f * acc0);
        Ekw[(size_t)(r0 + 1) * BD + o] = __expf(2.f * acc1);
    }
}

// Quad-rcp merge: acc += 1/x0 + 1/x1 + 1/x2 + 1/x3, one rcp per 4 terms.
// x = (1+E)/wv with |x| >= 1/|wv| (bounded away from 0); worst-case product
// p01*p23 ~ 1e36 < FLT_MAX; if it overflows, rcp(Inf)=0 drops a term whose
// true value is negligible anyway.
__device__ __forceinline__ void quad_acc(const float4 q, const float4 u4,
                                         const float4 e, float& acc) {
    float x0 = fmaf(q.x, e.x, u4.x);
    float x1 = fmaf(q.y, e.y, u4.y);
    float x2 = fmaf(q.z, e.z, u4.z);
    float x3 = fmaf(q.w, e.w, u4.w);
    float p01 = x0 * x1, p23 = x2 * x3;
    float num = fmaf(x0 + x1, p23, (x2 + x3) * p01);
    acc = fmaf(num, rcp_fast(p01 * p23), acc);
}

// K2: block = (b, 4 query rows), 512 threads = one thread per key j.
// The d-reduction is thread-local -> no 32KB partials LDS round-trip, no
// cross-wave reduce barrier, ~50 live VGPRs (cap 128 via bounds(512,4),
// 2 blocks/CU resident, LDS ~27KB).
// score_ij = sum_d wv_d*tanh(qu_jd+kw_id) = const - 2*sum_d 1/x_d,
// x_d = (1+exp(2qu_jd)exp(2kw_id))/wv_d = fma(Equ_jd, Ekw_id/wv_d, 1/wv_d).
__global__ __launch_bounds__(512, 4) void k_attn(const float* __restrict__ inp,
                                                 const float* __restrict__ Wv,
                                                 const float* __restrict__ Equ,
                                                 const float* __restrict__ Ekw,
                                                 float* __restrict__ out,
                                                 float* __restrict__ attn) {
    __shared__ float4 s_E2[32][4];     // 2 KB  [c][i]: Ekw[i0+i][4c..4c+3] * u
    __shared__ float4 s_u4[32];        // 0.5KB u[4c..4c+3] = 1/wv
    __shared__ float4 s_pT[SL];        // 8 KB  attn row-quad per j
    __shared__ float  s_fin[32 * BD];  // 16 KB P3 partials [g*4+row][d]
    __shared__ float4 s_red[8];        // per-wave softmax partial sums

    const int j   = threadIdx.x;       // key index 0..511
    const int blk = blockIdx.x;
    const int x   = blk & 7;           // XCD
    const int b   = x >> 1;            // batch pinned to XCD pair
    const int it  = (blk >> 3) * 2 + (x & 1);   // i-tile 0..127
    const int i0  = it * 4;

    if (j < BD) {
        const float* ek = Ekw + ((size_t)b * SL + i0) * BD + j;
        float u = rcp_fast(Wv[j]);
        int c = j >> 2, kk = j & 3;
        ((float*)&s_E2[c][0])[kk] = ek[0]        * u;
        ((float*)&s_E2[c][1])[kk] = ek[BD]       * u;
        ((float*)&s_E2[c][2])[kk] = ek[2 * BD]   * u;
        ((float*)&s_E2[c][3])[kk] = ek[3 * BD]   * u;
        ((float*)&s_u4[c])[kk]    = u;
    }
    __syncthreads();                                         // B1

    // ---- Phase 1: a_i = sum_d 1/x_d, fully in registers ----
    const float4* equ4 = (const float4*)(Equ) + (size_t)b * 32 * SL;
    float a0 = 0.f, a1 = 0.f, a2 = 0.f, a3 = 0.f;
    #pragma unroll 4
    for (int c = 0; c < 32; ++c) {
        float4 q  = equ4[c * SL + j];      // coalesced 1KB/wave, L2-local
        float4 u4 = s_u4[c];               // wave-uniform b128 broadcasts
        float4 e0 = s_E2[c][0];
        float4 e1 = s_E2[c][1];
        float4 e2 = s_E2[c][2];
        float4 e3 = s_E2[c][3];
        quad_acc(q, u4, e0, a0);
        quad_acc(q, u4, e1, a1);
        quad_acc(q, u4, e2, a2);
        quad_acc(q, u4, e3, a3);
    }

    // ---- Phase 2: softmax over j (no max-shift; |score| <= ~18 fits fp32) ----
    float p0 = __expf(-2.f * a0);
    float p1 = __expf(-2.f * a1);
    float p2 = __expf(-2.f * a2);
    float p3 = __expf(-2.f * a3);
    float r0 = p0, r1 = p1, r2 = p2, r3 = p3;
    #pragma unroll
    for (int off = 32; off > 0; off >>= 1) {
        r0 += __shfl_xor(r0, off, 64);
        r1 += __shfl_xor(r1, off, 64);
        r2 += __shfl_xor(r2, off, 64);
        r3 += __shfl_xor(r3, off, 64);
    }
    const int w = j >> 6, ln = j & 63;
    if (ln == 0) s_red[w] = make_float4(r0, r1, r2, r3);
    __syncthreads();                                         // B2
    float4 d0 = s_red[0], d1 = s_red[1], d2 = s_red[2], d3 = s_red[3];
    float4 d4 = s_red[4], d5 = s_red[5], d6 = s_red[6], d7 = s_red[7];
    float dx = ((d0.x + d1.x) + (d2.x + d3.x)) + ((d4.x + d5.x) + (d6.x + d7.x));
    float dy = ((d0.y + d1.y) + (d2.y + d3.y)) + ((d4.y + d5.y) + (d6.y + d7.y));
    float dz = ((d0.z + d1.z) + (d2.z + d3.z)) + ((d4.z + d5.z) + (d6.z + d7.z));
    float dw = ((d0.w + d1.w) + (d2.w + d3.w)) + ((d4.w + d5.w) + (d6.w + d7.w));
    float n0 = p0 * rcp_fast(dx);
    float n1 = p1 * rcp_fast(dy);
    float n2 = p2 * rcp_fast(dz);
    float n3 = p3 * rcp_fast(dw);
    float* ap = attn + ((size_t)b * SL + i0) * SL + j;       // coalesced
    ap[0]      = n0;
    ap[SL]     = n1;
    ap[2 * SL] = n2;
    ap[3 * SL] = n3;
    s_pT[j] = make_float4(n0, n1, n2, n3);
    __syncthreads();                                         // B3

    // ---- Phase 3: out = attn @ inp; wave g covers j = g*64..g*64+63 ----
    const int g  = j >> 6;                  // 8 waves
    const int dq = j & 31;                  // d-quad
    const int rh = (j >> 5) & 1;            // row pair
    const float4* inp4 = (const float4*)(inp) + (size_t)b * SL * 32;
    float4 accA = make_float4(0.f, 0.f, 0.f, 0.f);
    float4 accB = make_float4(0.f, 0.f, 0.f, 0.f);
    #pragma unroll 4
    for (int tt = 0; tt < 64; ++tt) {
        int jr = g * 64 + tt;
        float4 xv = inp4[jr * 32 + dq];                    // L2-local b128
        float2 pp = *((const float2*)&s_pT[jr] + rh);      // 2-addr LDS broadcast
        accA.x = fmaf(pp.x, xv.x, accA.x); accA.y = fmaf(pp.x, xv.y, accA.y);
        accA.z = fmaf(pp.x, xv.z, accA.z); accA.w = fmaf(pp.x, xv.w, accA.w);
        accB.x = fmaf(pp.y, xv.x, accB.x); accB.y = fmaf(pp.y, xv.y, accB.y);
        accB.z = fmaf(pp.y, xv.z, accB.z); accB.w = fmaf(pp.y, xv.w, accB.w);
    }
    *(float4*)&s_fin[((g * 4) + rh * 2 + 0) * BD + dq * 4] = accA;
    *(float4*)&s_fin[((g * 4) + rh * 2 + 1) * BD + dq * 4] = accB;
    __syncthreads();                                         // B4
    {
        int row = j >> 7, d = j & 127;
        float s = 0.f;
        #pragma unroll
        for (int gg = 0; gg < 8; ++gg)
            s += s_fin[(gg * 4 + row) * BD + d];           // conflict-free
        out[((size_t)b * SL + i0 + row) * BD + d] = s;     // coalesced
    }
}

extern "C" void kernel_launch(void* const* d_in, const int* in_sizes, int n_in,
                              void* d_out, int out_size, void* d_ws, size_t ws_size,
                              hipStream_t stream) {
    const float* inp = (const float*)d_in[0];
    const float* Wu  = (const float*)d_in[1];
    const float* Ww  = (const float*)d_in[2];
    const float* Wv  = (const float*)d_in[3];

    float* out  = (float*)d_out;
    float* attn = out + (size_t)NB * SL * BD;     // out (B,L,D) then attn (B,L,L)

    float* ws   = (float*)d_ws;
    float* Equ  = ws;                             // (B, D/4, L, 4) packed exp(2*qu)
    float* Ekw  = Equ + (size_t)NB * BD * SL;     // (B, L, D) exp(2*kw)
    float* WuT  = Ekw + (size_t)NB * SL * BD;
    float* WwT  = WuT + BD * BD;

    k_tr  <<<BD * BD / 256, 256, 0, stream>>>(Wu, Ww, WuT, WwT);
    k_qk  <<<NB * SL / 2, 256, 0, stream>>>(inp, WuT, WwT, Equ, Ekw);
    k_attn<<<NB * SL / 4, 512, 0, stream>>>(inp, Wv, Equ, Ekw, out, attn);
}